// Round 4
// baseline (3762.317 us; speedup 1.0000x reference)
//
#include <hip/hip_runtime.h>
#include <math.h>

// ---- problem constants ----
#define BB 64
#define IMG 224
#define PP 16
#define DD 768
#define NH 12
#define NL 12
#define GG 14
#define TT 196
#define HD 64

typedef __attribute__((ext_vector_type(8))) short short8;
typedef __attribute__((ext_vector_type(4))) float floatx4;

__device__ __forceinline__ unsigned short f2bfu(float f) {
    union { float f; unsigned int u; } v; v.f = f;
    unsigned int r = v.u + 0x7FFFu + ((v.u >> 16) & 1u);   // RNE
    return (unsigned short)(r >> 16);
}

__device__ __forceinline__ void g2lds16(const void* g, void* l) {
    __builtin_amdgcn_global_load_lds(
        (const __attribute__((address_space(1))) unsigned int*)g,
        (__attribute__((address_space(3))) unsigned int*)l, 16, 0, 0);
}

// ================= bf16 MFMA GEMM:  C[M,N] = A[M,K] @ W[N,K]^T + bias =================
// 128x128 tile, BK=32, 4 waves each computing 64x64 via 4x4 MFMA 16x16x32 tiles.
// MODE 0: fp32 out + bias.        MODE 1: bias + exact GELU, bf16 out.
// MODE 2: fp32 out + bias + pos_embed[row % TT].  MODE 3: bias, bf16 out.
// MODE 4: split-K fp32 partials; grid = splits*MB*nb; split s handles K-chunk
//         [s*klen, (s+1)*klen), writes Cf + s*M*N; bias only on split 0.
template <int MODE>
__global__ __launch_bounds__(256) void gemm_mfma(const unsigned short* __restrict__ A,
                                                 const unsigned short* __restrict__ W,
                                                 const float* __restrict__ bias,
                                                 float* __restrict__ Cf,
                                                 unsigned short* __restrict__ Cb,
                                                 int M, int N, int K,
                                                 const float* __restrict__ pose,
                                                 int klen, int splits) {
    __shared__ unsigned short As[128 * 32];
    __shared__ unsigned short Bs[128 * 32];
    const int nb = N >> 7;
    int bid = blockIdx.x;
    int split = 0;
    if (MODE == 4) {
        const int per = gridDim.x / splits;
        split = bid / per;
        bid -= split * per;
    }
    const int m0 = (bid / nb) << 7;
    const int n0 = (bid % nb) << 7;
    const int tid = threadIdx.x;
    const int lane = tid & 63;
    const int wave = tid >> 6;
    const int wm = (wave >> 1) << 6;
    const int wn = (wave & 1) << 6;
    const int fr = lane & 15;          // frag row (A) / col (B)
    const int fk = (lane >> 4) << 3;   // frag k offset

    const unsigned short* Ag = A + (size_t)(m0 + (tid >> 2)) * K + (tid & 3) * 8;
    const unsigned short* Wg = W + (size_t)(n0 + (tid >> 2)) * K + (tid & 3) * 8;
    unsigned short* lA = As + tid * 8;
    unsigned short* lB = Bs + tid * 8;
    const size_t rowskip = (size_t)64 * K;

    floatx4 acc[4][4];
#pragma unroll
    for (int i = 0; i < 4; ++i)
#pragma unroll
        for (int j = 0; j < 4; ++j) acc[i][j] = (floatx4){0.f, 0.f, 0.f, 0.f};

    const int kstart = (MODE == 4) ? split * klen : 0;
    const int kend = (MODE == 4) ? kstart + klen : K;
    for (int kt = kstart; kt < kend; kt += 32) {
        g2lds16(Ag + kt, lA);
        g2lds16(Ag + kt + rowskip, lA + 64 * 32);
        g2lds16(Wg + kt, lB);
        g2lds16(Wg + kt + rowskip, lB + 64 * 32);
        __syncthreads();
        short8 af[4], bf[4];
#pragma unroll
        for (int i = 0; i < 4; ++i) {
            af[i] = *(const short8*)(As + (wm + i * 16 + fr) * 32 + fk);
            bf[i] = *(const short8*)(Bs + (wn + i * 16 + fr) * 32 + fk);
        }
#pragma unroll
        for (int i = 0; i < 4; ++i)
#pragma unroll
            for (int j = 0; j < 4; ++j)
                acc[i][j] = __builtin_amdgcn_mfma_f32_16x16x32_bf16(af[i], bf[j], acc[i][j], 0, 0, 0);
        __syncthreads();
    }

    float* Cfs = (MODE == 4) ? Cf + (size_t)split * M * N : Cf;
    const int r0 = (lane >> 4) << 2;   // C/D: row=(lane>>4)*4+reg, col=lane&15 (m89-verified)
#pragma unroll
    for (int j = 0; j < 4; ++j) {
        const int col = n0 + wn + j * 16 + fr;
        float bv = bias ? bias[col] : 0.f;
        if (MODE == 4 && split != 0) bv = 0.f;
#pragma unroll
        for (int i = 0; i < 4; ++i) {
            const int row = m0 + wm + i * 16 + r0;
#pragma unroll
            for (int r = 0; r < 4; ++r) {
                float v = acc[i][j][r] + bv;
                if (MODE == 1) {
                    v = 0.5f * v * (1.0f + erff(v * 0.70710678118654752f));
                    Cb[(size_t)(row + r) * N + col] = f2bfu(v);
                } else if (MODE == 2) {
                    const int tok = (row + r) % TT;
                    Cfs[(size_t)(row + r) * N + col] = v + pose[(size_t)tok * DD + col];
                } else if (MODE == 3) {
                    Cb[(size_t)(row + r) * N + col] = f2bfu(v);
                } else {
                    Cfs[(size_t)(row + r) * N + col] = v;
                }
            }
        }
    }
}

// ================= im2col of x into bf16 A[B*T, 768];  k = c*256 + py*16 + px =================
__global__ __launch_bounds__(256) void im2col_bf16(const float* __restrict__ x,
                                                   unsigned short* __restrict__ A) {
    const int u = blockIdx.x * 256 + threadIdx.x;       // total B*T*768/4 = 2408448
    const int m = u / 192;                              // row (b*TT + token)
    const int kq = (u - m * 192) * 4;                   // k offset, multiple of 4
    const int b = m / TT, token = m - b * TT;
    const int gy = token / GG, gx = token - gy * GG;
    const int c = kq >> 8, py = (kq >> 4) & 15, px = kq & 15;
    const float* src = x + ((size_t)b * 3 + c) * (IMG * IMG)
                         + (size_t)(gy * PP + py) * IMG + gx * PP + px;
    float4 v = *(const float4*)src;
    ushort4 o;
    o.x = f2bfu(v.x); o.y = f2bfu(v.y); o.z = f2bfu(v.z); o.w = f2bfu(v.w);
    *(ushort4*)(A + (size_t)m * DD + kq) = o;
}

// ================= patch embedding fp32 fallback =================
__global__ __launch_bounds__(256) void patch_embed_gemm(const float* __restrict__ x,
                                                        const float* __restrict__ W,
                                                        const float* __restrict__ bias,
                                                        const float* __restrict__ pos,
                                                        float* __restrict__ t) {
    __shared__ float Asm[16][68];
    __shared__ float Bsm[16][68];
    const int m0 = (blockIdx.x / 12) * 64;
    const int n0 = (blockIdx.x % 12) * 64;
    const int tid = threadIdx.x;
    const int lr = tid >> 2;
    const int lk = (tid & 3) * 4;
    const int tx = tid & 15, ty = tid >> 4;

    const int m = m0 + lr;
    const int b = m / TT, token = m % TT;
    const int gy = token / GG, gx = token % GG;
    const float* xrow = x + (size_t)b * (3 * IMG * IMG) + (gy * PP) * IMG + gx * PP;

    float acc[4][4] = {};
    for (int kt = 0; kt < 48; ++kt) {
        int c = kt >> 4, py = kt & 15;
        float4 av = *(const float4*)(xrow + ((size_t)c * IMG + py) * IMG + lk);
        float4 bv = *(const float4*)(W + (size_t)(n0 + lr) * DD + kt * 16 + lk);
        __syncthreads();
        Asm[lk + 0][lr] = av.x; Asm[lk + 1][lr] = av.y; Asm[lk + 2][lr] = av.z; Asm[lk + 3][lr] = av.w;
        Bsm[lk + 0][lr] = bv.x; Bsm[lk + 1][lr] = bv.y; Bsm[lk + 2][lr] = bv.z; Bsm[lk + 3][lr] = bv.w;
        __syncthreads();
#pragma unroll
        for (int k = 0; k < 16; ++k) {
            float4 a4 = *(const float4*)&Asm[k][ty * 4];
            float4 b4 = *(const float4*)&Bsm[k][tx * 4];
            float a[4] = {a4.x, a4.y, a4.z, a4.w};
            float b2[4] = {b4.x, b4.y, b4.z, b4.w};
#pragma unroll
            for (int i = 0; i < 4; ++i)
#pragma unroll
                for (int j = 0; j < 4; ++j) acc[i][j] += a[i] * b2[j];
        }
    }
    float4 bi = *(const float4*)(bias + n0 + tx * 4);
#pragma unroll
    for (int i = 0; i < 4; ++i) {
        int mi = m0 + ty * 4 + i;
        int tok = mi % TT;
        float4 p4 = *(const float4*)(pos + (size_t)tok * DD + n0 + tx * 4);
        float4 o;
        o.x = acc[i][0] + bi.x + p4.x;
        o.y = acc[i][1] + bi.y + p4.y;
        o.z = acc[i][2] + bi.z + p4.z;
        o.w = acc[i][3] + bi.w + p4.w;
        *(float4*)(t + (size_t)mi * DD + n0 + tx * 4) = o;
    }
}

// ================= mask scan: order list + lengths + pad flags (wave-parallel) =================
__global__ __launch_bounds__(64) void scan_mask(const unsigned char* __restrict__ mask8,
                                                int* __restrict__ order,
                                                int* __restrict__ lengths,
                                                float* __restrict__ pad_out, int Sc) {
    const int b = blockIdx.x;
    const int lane = threadIdx.x;
    const unsigned int* w = (const unsigned int*)mask8;
    unsigned int v0 = w[lane];
    unsigned long long bf = __ballot(v0 == 0x3F800000u);
    unsigned long long bg = __ballot(v0 != 0x3F800000u && v0 > 1u);
    const int mode = bf ? 2 : (bg ? 1 : 0);   // 0=int32, 1=uint8, 2=float32
    int cnt = 0;
    for (int i0 = 0; i0 < TT; i0 += 64) {
        const int i = i0 + lane;
        int mv = 0;
        if (i < TT) {
            if (mode == 0) mv = mask8[4 * (b * TT + i)];
            else if (mode == 1) mv = mask8[b * TT + i];
            else mv = (w[b * TT + i] != 0u);
        }
        unsigned long long bal = __ballot(mv != 0);
        int pre = __popcll(bal & ((1ull << lane) - 1ull));
        if (mv) order[b * Sc + cnt + pre] = i;
        cnt += __popcll(bal);
    }
    if (lane == 0) lengths[b] = cnt;
    for (int s = lane; s < Sc; s += 64) pad_out[b * Sc + s] = (s < cnt) ? 0.f : 1.f;
}

// ================= gathered copy: fp32 ctx + bf16 ctx, grid-stride float4 =================
__global__ __launch_bounds__(256) void gather_copy(const float* __restrict__ t,
                                                   const int* __restrict__ order,
                                                   const int* __restrict__ lengths,
                                                   float* __restrict__ ctx,
                                                   unsigned short* __restrict__ ctxb, int Sc) {
    const int total = BB * Sc * (DD / 4);
    for (int u = blockIdx.x * 256 + threadIdx.x; u < total; u += gridDim.x * 256) {
        const int row = u / 192, q = u - row * 192;
        const int b = row / Sc, s = row - b * Sc;
        float4 v = {0.f, 0.f, 0.f, 0.f};
        if (s < lengths[b])
            v = *(const float4*)(t + ((size_t)b * TT + order[b * Sc + s]) * DD + q * 4);
        *(float4*)(ctx + (size_t)row * DD + q * 4) = v;
        ushort4 o;
        o.x = f2bfu(v.x); o.y = f2bfu(v.y); o.z = f2bfu(v.z); o.w = f2bfu(v.w);
        *(ushort4*)(ctxb + (size_t)row * DD + q * 4) = o;
    }
}

// ================= MFMA flash attention (Sc <= 128): block=(b,h), 4 waves =================
template <int P>
__global__ __launch_bounds__(256) void attn_mfma(const unsigned short* __restrict__ qkv,
                                                 const int* __restrict__ lengths,
                                                 unsigned short* __restrict__ outp, int Sc) {
    constexpr int PS = 64 * P;
    constexpr int KROW = 128;        // Kb row bytes (64 bf16)
    constexpr int VROW = PS * 2;     // Vt/Pw row bytes
    extern __shared__ unsigned char smraw[];
    unsigned char* Kb = smraw;                   // [PS][KROW]
    unsigned char* Vt = Kb + PS * KROW;          // [64][VROW]
    unsigned char* Pw = Vt + 64 * VROW;          // [4][16P][VROW]
    const int b = blockIdx.x / NH, h = blockIdx.x % NH;
    const int len = lengths[b];
    const int tid = threadIdx.x;
    const int lane = tid & 63, wave = tid >> 6;
    const int fr = lane & 15, g = lane >> 4;
    const size_t qbase = (size_t)b * Sc * (3 * DD) + h * HD;

    for (int c = tid; c < PS * 8; c += 256) {
        const int s = c >> 3, kg = c & 7;
        short8 kv = {0, 0, 0, 0, 0, 0, 0, 0};
        short8 vv = {0, 0, 0, 0, 0, 0, 0, 0};
        if (s < len) {
            kv = *(const short8*)(qkv + qbase + (size_t)s * (3 * DD) + DD + kg * 8);
            vv = *(const short8*)(qkv + qbase + (size_t)s * (3 * DD) + 2 * DD + kg * 8);
        }
        *(short8*)(Kb + s * KROW + ((kg * 16) ^ ((s & 7) << 4))) = kv;
#pragma unroll
        for (int e = 0; e < 8; ++e) {
            const int d = kg * 8 + e;
            *(unsigned short*)(Vt + d * VROW + ((s * 2) ^ ((d & 7) << 4))) =
                (unsigned short)vv[e];
        }
    }
    __syncthreads();

    const int wq0 = wave * 16 * P;
    short8 qf[P][2];
#pragma unroll
    for (int i = 0; i < P; ++i) {
        int qr = wq0 + i * 16 + fr; if (qr >= Sc) qr = Sc - 1;
#pragma unroll
        for (int ks = 0; ks < 2; ++ks)
            qf[i][ks] = *(const short8*)(qkv + qbase + (size_t)qr * (3 * DD) + ks * 32 + g * 8);
    }

    floatx4 sacc[P][4 * P];
#pragma unroll
    for (int i = 0; i < P; ++i)
#pragma unroll
        for (int j = 0; j < 4 * P; ++j) sacc[i][j] = (floatx4){0.f, 0.f, 0.f, 0.f};
#pragma unroll
    for (int j = 0; j < 4 * P; ++j) {
        const int key = j * 16 + fr;
#pragma unroll
        for (int ks = 0; ks < 2; ++ks) {
            short8 kf = *(const short8*)(Kb + key * KROW + ((ks * 64 + g * 16) ^ ((key & 7) << 4)));
#pragma unroll
            for (int i = 0; i < P; ++i)
                sacc[i][j] = __builtin_amdgcn_mfma_f32_16x16x32_bf16(qf[i][ks], kf, sacc[i][j], 0, 0, 0);
        }
    }

    unsigned char* mypw = Pw + (size_t)wave * (16 * P) * VROW;
#pragma unroll
    for (int i = 0; i < P; ++i) {
#pragma unroll
        for (int r = 0; r < 4; ++r) {
            float vals[4 * P];
            float vmax = -1e30f;
#pragma unroll
            for (int j = 0; j < 4 * P; ++j) {
                float s = sacc[i][j][r] * 0.125f;
                if (j * 16 + fr >= len) s = -1e30f;
                vals[j] = s;
                vmax = fmaxf(vmax, s);
            }
#pragma unroll
            for (int off = 1; off < 16; off <<= 1) vmax = fmaxf(vmax, __shfl_xor(vmax, off, 64));
            float lsum = 0.f;
#pragma unroll
            for (int j = 0; j < 4 * P; ++j) { vals[j] = __expf(vals[j] - vmax); lsum += vals[j]; }
#pragma unroll
            for (int off = 1; off < 16; off <<= 1) lsum += __shfl_xor(lsum, off, 64);
            const float rl = 1.0f / lsum;
            const int lr = i * 16 + g * 4 + r;
            unsigned char* rowp = mypw + lr * VROW;
            const int sw = (lr & 7) << 4;
#pragma unroll
            for (int j = 0; j < 4 * P; ++j)
                *(unsigned short*)(rowp + (((j * 16 + fr) * 2) ^ sw)) = f2bfu(vals[j] * rl);
        }
    }

    floatx4 oacc[P][4];
#pragma unroll
    for (int i = 0; i < P; ++i)
#pragma unroll
        for (int dt = 0; dt < 4; ++dt) oacc[i][dt] = (floatx4){0.f, 0.f, 0.f, 0.f};
#pragma unroll
    for (int kk = 0; kk < 2 * P; ++kk) {
        short8 pa[P];
#pragma unroll
        for (int i = 0; i < P; ++i) {
            const int lr = i * 16 + fr;
            pa[i] = *(const short8*)(mypw + lr * VROW + ((kk * 64 + g * 16) ^ ((lr & 7) << 4)));
        }
#pragma unroll
        for (int dt = 0; dt < 4; ++dt) {
            const int d = dt * 16 + fr;
            short8 vb = *(const short8*)(Vt + d * VROW + ((kk * 64 + g * 16) ^ ((d & 7) << 4)));
#pragma unroll
            for (int i = 0; i < P; ++i)
                oacc[i][dt] = __builtin_amdgcn_mfma_f32_16x16x32_bf16(pa[i], vb, oacc[i][dt], 0, 0, 0);
        }
    }

#pragma unroll
    for (int i = 0; i < P; ++i) {
#pragma unroll
        for (int r = 0; r < 4; ++r) {
            const int qr = wq0 + i * 16 + g * 4 + r;
            if (qr < Sc) {
#pragma unroll
                for (int dt = 0; dt < 4; ++dt)
                    outp[((size_t)b * Sc + qr) * DD + h * HD + dt * 16 + fr] = f2bfu(oacc[i][dt][r]);
            }
        }
    }
}

// ================= attention VALU fallback (Sc > 128) =================
template <int P>   // P = ceil(Sc/64), Ks has P*64 rows
__global__ __launch_bounds__(512) void attn_v3(const float* __restrict__ qkv,
                                               const int* __restrict__ lengths,
                                               unsigned short* __restrict__ outp, int Sc) {
    extern __shared__ float smem[];
    float* pst = smem;                       // [8][P*64]
    float* qst = pst + 8 * P * 64;           // [8][66]
    float* Ks  = qst + 8 * 66;               // [P*64][66]
    float* Vs  = Ks + P * 64 * 66;           // [Sc][66]
    const int b = blockIdx.x / NH, h = blockIdx.x % NH;
    const int len = lengths[b];
    const int tid = threadIdx.x;
    const float* base = qkv + (size_t)b * Sc * (3 * DD) + h * HD;

    for (int idx = tid; idx < Sc * HD; idx += 512) {
        int s = idx >> 6, d = idx & 63;
        Ks[s * 66 + d] = base[(size_t)s * (3 * DD) + DD + d];
        Vs[s * 66 + d] = base[(size_t)s * (3 * DD) + 2 * DD + d];
    }
    __syncthreads();

    const int wave = tid >> 6, lane = tid & 63;
    float* qw = qst + wave * 66;
    float* pw = pst + wave * P * 64;

    for (int q = wave; q < Sc; q += 8) {
        float qv = base[(size_t)q * (3 * DD) + lane];
        qw[lane] = qv;
        float s0 = 0.f, s1 = 0.f, s2 = 0.f, s3 = 0.f;
#pragma unroll
        for (int d0 = 0; d0 < 64; d0 += 2) {
            float2 q2 = *(const float2*)(qw + d0);
            float2 k0 = *(const float2*)(Ks + lane * 66 + d0);
            s0 += q2.x * k0.x + q2.y * k0.y;
            if (P > 1) {
                float2 k1 = *(const float2*)(Ks + (lane + 64) * 66 + d0);
                s1 += q2.x * k1.x + q2.y * k1.y;
            }
            if (P > 2) {
                float2 k2 = *(const float2*)(Ks + (lane + 128) * 66 + d0);
                s2 += q2.x * k2.x + q2.y * k2.y;
            }
            if (P > 3) {
                float2 k3 = *(const float2*)(Ks + (lane + 192) * 66 + d0);
                s3 += q2.x * k3.x + q2.y * k3.y;
            }
        }
        s0 = (lane < len) ? s0 * 0.125f : -1e30f;
        if (P > 1) s1 = (64 + lane < len) ? s1 * 0.125f : -1e30f;
        if (P > 2) s2 = (128 + lane < len) ? s2 * 0.125f : -1e30f;
        if (P > 3) s3 = (192 + lane < len) ? s3 * 0.125f : -1e30f;
        float m = s0;
        if (P > 1) m = fmaxf(m, s1);
        if (P > 2) m = fmaxf(m, s2);
        if (P > 3) m = fmaxf(m, s3);
#pragma unroll
        for (int off = 32; off; off >>= 1) m = fmaxf(m, __shfl_xor(m, off, 64));
        s0 = __expf(s0 - m);
        if (P > 1) s1 = __expf(s1 - m);
        if (P > 2) s2 = __expf(s2 - m);
        if (P > 3) s3 = __expf(s3 - m);
        float l = s0;
        if (P > 1) l += s1;
        if (P > 2) l += s2;
        if (P > 3) l += s3;
#pragma unroll
        for (int off = 32; off; off >>= 1) l += __shfl_xor(l, off, 64);
        pw[lane] = s0;
        if (P > 1) pw[64 + lane] = s1;
        if (P > 2) pw[128 + lane] = s2;
        if (P > 3) pw[192 + lane] = s3;
        float a0 = 0.f, a1 = 0.f, a2 = 0.f, a3 = 0.f;
        const int j4 = len & ~3;
        for (int j = 0; j < j4; j += 4) {
            float4 p4 = *(const float4*)(pw + j);
            a0 += p4.x * Vs[(j + 0) * 66 + lane];
            a1 += p4.y * Vs[(j + 1) * 66 + lane];
            a2 += p4.z * Vs[(j + 2) * 66 + lane];
            a3 += p4.w * Vs[(j + 3) * 66 + lane];
        }
        for (int j = j4; j < len; ++j) a0 += pw[j] * Vs[j * 66 + lane];
        float acc = (a0 + a1) + (a2 + a3);
        outp[((size_t)b * Sc + q) * DD + h * HD + lane] = f2bfu(acc / l);
    }
}

// ================= layernorm (+residual = x + sum of nparts partials) =================
__global__ __launch_bounds__(256) void ln_kernel(const float* __restrict__ x,
                                                 const float* __restrict__ parts,
                                                 int nparts, size_t pstride,
                                                 const float* __restrict__ g,
                                                 const float* __restrict__ beta,
                                                 float* __restrict__ outf,
                                                 unsigned short* __restrict__ outb) {
    __shared__ float red[4];
    const size_t row = blockIdx.x;
    const int tid = threadIdx.x;
    float v[3];
#pragma unroll
    for (int i = 0; i < 3; ++i) {
        int d = tid + i * 256;
        float t0 = x[row * DD + d];
        for (int s = 0; s < nparts; ++s) t0 += parts[s * pstride + row * DD + d];
        v[i] = t0;
    }
    float s = v[0] + v[1] + v[2];
#pragma unroll
    for (int off = 32; off; off >>= 1) s += __shfl_xor(s, off, 64);
    if ((tid & 63) == 0) red[tid >> 6] = s;
    __syncthreads();
    float mean = (red[0] + red[1] + red[2] + red[3]) * (1.0f / 768.0f);
    __syncthreads();
    float vs = 0.f;
#pragma unroll
    for (int i = 0; i < 3; ++i) { float d0 = v[i] - mean; vs += d0 * d0; }
#pragma unroll
    for (int off = 32; off; off >>= 1) vs += __shfl_xor(vs, off, 64);
    if ((tid & 63) == 0) red[tid >> 6] = vs;
    __syncthreads();
    float var = (red[0] + red[1] + red[2] + red[3]) * (1.0f / 768.0f);
    float inv = rsqrtf(var + 1e-5f);
#pragma unroll
    for (int i = 0; i < 3; ++i) {
        int d = tid + i * 256;
        float o = (v[i] - mean) * inv * g[d] + beta[d];
        outf[row * DD + d] = o;
        if (outb) outb[row * DD + d] = f2bfu(o);
    }
}

// ================= fp32 -> bf16 conversion of up to 4 weight mats =================
__global__ __launch_bounds__(256) void convert4_bf16(const float* __restrict__ a, int na,
                                                     const float* __restrict__ b, int nb,
                                                     const float* __restrict__ c, int nc,
                                                     const float* __restrict__ d, int nd,
                                                     unsigned short* __restrict__ dst) {
    const int total4 = (na + nb + nc + nd) >> 2;
    for (int u = blockIdx.x * 256 + threadIdx.x; u < total4; u += gridDim.x * 256) {
        int e = u << 2;
        const float* src; int off;
        if (e < na) { src = a; off = e; }
        else if (e < na + nb) { src = b; off = e - na; }
        else if (e < na + nb + nc) { src = c; off = e - na - nb; }
        else { src = d; off = e - na - nb - nc; }
        float4 v = *(const float4*)(src + off);
        ushort4 o;
        o.x = f2bfu(v.x); o.y = f2bfu(v.y); o.z = f2bfu(v.z); o.w = f2bfu(v.w);
        *(ushort4*)(dst + e) = o;
    }
}

extern "C" void kernel_launch(void* const* d_in, const int* in_sizes, int n_in,
                              void* d_out, int out_size, void* d_ws, size_t ws_size,
                              hipStream_t stream) {
    (void)in_sizes; (void)n_in; (void)ws_size;
    const float* x          = (const float*)d_in[0];
    const unsigned char* mk = (const unsigned char*)d_in[1];
    const float* patch_w    = (const float*)d_in[2];
    const float* patch_b    = (const float*)d_in[3];
    const float* pos        = (const float*)d_in[4];
    const float* in_proj_w  = (const float*)d_in[5];
    const float* in_proj_b  = (const float*)d_in[6];
    const float* out_w      = (const float*)d_in[7];
    const float* out_b      = (const float*)d_in[8];
    const float* ln1_g      = (const float*)d_in[9];
    const float* ln1_b      = (const float*)d_in[10];
    const float* ffn_w1     = (const float*)d_in[11];
    const float* ffn_b1     = (const float*)d_in[12];
    const float* ffn_w2     = (const float*)d_in[13];
    const float* ffn_b2     = (const float*)d_in[14];
    const float* ln2_g      = (const float*)d_in[15];
    const float* ln2_b      = (const float*)d_in[16];
    const float* norm_g     = (const float*)d_in[17];
    const float* norm_b     = (const float*)d_in[18];
    float* out = (float*)d_out;

    const int Sc = out_size / (BB * (DD + 1));
    const int M = BB * Sc;
    const int Mp = ((M + 127) / 128) * 128;
    const int MB = Mp / 128;

    // ---- workspace layout ----
    float* t_f   = (float*)d_ws;                          // B*T*D
    float* qkv_f = t_f + (size_t)BB * TT * DD;            // Mp*2304 (also split-K partials)
    float* ctx_f = qkv_f + (size_t)Mp * 2304;             // Mp*768
    float* y_f   = ctx_f + (size_t)Mp * DD;               // Mp*768 (unused on split path)
    unsigned short* ctx_b  = (unsigned short*)(y_f + (size_t)Mp * DD);  // Mp*768
    unsigned short* attn_b = ctx_b + (size_t)Mp * DD;                    // Mp*768
    unsigned short* h_b    = attn_b + (size_t)Mp * DD;                   // Mp*3072
    unsigned short* wq     = h_b + (size_t)Mp * 4 * DD;                  // 2304*768
    unsigned short* wo     = wq + (size_t)3 * DD * DD;                   // 768*768
    unsigned short* w1     = wo + (size_t)DD * DD;                       // 3072*768
    unsigned short* w2     = w1 + (size_t)4 * DD * DD;                   // 768*3072
    int* lengths = (int*)(w2 + (size_t)4 * DD * DD);
    unsigned short* qkv_b = (unsigned short*)qkv_f;       // bf16 alias (MFMA attn path)
    int* order = (int*)qkv_f;  // scratch alias: dead between patch gemm and layer-0 QKV
    const size_t pstr = (size_t)Mp * DD;                  // split-K partial stride

    // ---- patch embedding (bf16 MFMA fast path) ----
    const bool fast_patch =
        ((size_t)Mp * 2304 * sizeof(float) >= (size_t)BB * TT * DD * sizeof(unsigned short)) &&
        ((size_t)Mp * DD * sizeof(unsigned short) >= (size_t)DD * DD * sizeof(unsigned short));
    if (fast_patch) {
        unsigned short* Apatch = ((unsigned short*)qkv_f) + (size_t)BB * 256;  // keep order area clear
        unsigned short* wpatch = ctx_b;
        im2col_bf16<<<(BB * TT * DD / 4) / 256, 256, 0, stream>>>(x, Apatch);
        convert4_bf16<<<1024, 256, 0, stream>>>(patch_w, DD * DD, nullptr, 0,
                                                nullptr, 0, nullptr, 0, wpatch);
        gemm_mfma<2><<<(BB * TT / 128) * (DD / 128), 256, 0, stream>>>(
            Apatch, wpatch, patch_b, t_f, nullptr, BB * TT, DD, DD, pos, DD, 1);
        order = (int*)(Apatch + (size_t)BB * TT * DD);   // after A, still inside qkv_f
    } else {
        patch_embed_gemm<<<TT * 12, 256, 0, stream>>>(x, patch_w, patch_b, pos, t_f);
    }
    scan_mask<<<BB, 64, 0, stream>>>(mk, order, lengths, out + (size_t)M * DD, Sc);
    {
        int total4 = BB * Sc * (DD / 4);
        int gblocks = (total4 + 255) / 256; if (gblocks > 2048) gblocks = 2048;
        gather_copy<<<gblocks, 256, 0, stream>>>(t_f, order, lengths, ctx_f, ctx_b, Sc);
    }

    int P = (Sc + 63) / 64; if (P > 4) P = 4;
    const bool mfma_attn = (P <= 2);
    size_t smem_attn;
    if (mfma_attn) {
        smem_attn = (size_t)(64 * P) * 128 * (2 + P);
        const void* fp = (P == 1) ? (const void*)attn_mfma<1> : (const void*)attn_mfma<2>;
        (void)hipFuncSetAttribute(fp, hipFuncAttributeMaxDynamicSharedMemorySize, (int)smem_attn);
    } else {
        smem_attn = (size_t)(8 * P * 64 + 8 * 66 + (size_t)(P * 64 + Sc) * 66) * sizeof(float);
        const void* fp = (P == 3) ? (const void*)attn_v3<3> : (const void*)attn_v3<4>;
        (void)hipFuncSetAttribute(fp, hipFuncAttributeMaxDynamicSharedMemorySize, (int)smem_attn);
    }

    for (int l = 0; l < NL; ++l) {
        convert4_bf16<<<1024, 256, 0, stream>>>(
            in_proj_w + (size_t)l * 3 * DD * DD, 3 * DD * DD,
            out_w + (size_t)l * DD * DD, DD * DD,
            ffn_w1 + (size_t)l * 4 * DD * DD, 4 * DD * DD,
            ffn_w2 + (size_t)l * 4 * DD * DD, 4 * DD * DD, wq);
        if (mfma_attn) {
            gemm_mfma<3><<<MB * 18, 256, 0, stream>>>(ctx_b, wq, in_proj_b + (size_t)l * 3 * DD,
                                                      nullptr, qkv_b, Mp, 3 * DD, DD, nullptr, DD, 1);
            if (P == 1)
                attn_mfma<1><<<BB * NH, 256, smem_attn, stream>>>(qkv_b, lengths, attn_b, Sc);
            else
                attn_mfma<2><<<BB * NH, 256, smem_attn, stream>>>(qkv_b, lengths, attn_b, Sc);
        } else {
            gemm_mfma<0><<<MB * 18, 256, 0, stream>>>(ctx_b, wq, in_proj_b + (size_t)l * 3 * DD,
                                                      qkv_f, nullptr, Mp, 3 * DD, DD, nullptr, DD, 1);
            if (P == 3)
                attn_v3<3><<<BB * NH, 512, smem_attn, stream>>>(qkv_f, lengths, attn_b, Sc);
            else
                attn_v3<4><<<BB * NH, 512, smem_attn, stream>>>(qkv_f, lengths, attn_b, Sc);
        }
        // WO: split-K x2 into qkv_f partials (qkv consumed by attn already)
        gemm_mfma<4><<<2 * MB * 6, 256, 0, stream>>>(attn_b, wo, out_b + (size_t)l * DD,
                                                     qkv_f, nullptr, Mp, DD, DD, nullptr, 384, 2);
        ln_kernel<<<M, 256, 0, stream>>>(ctx_f, qkv_f, 2, pstr, ln1_g + (size_t)l * DD,
                                         ln1_b + (size_t)l * DD, ctx_f, ctx_b);
        gemm_mfma<1><<<MB * 24, 256, 0, stream>>>(ctx_b, w1, ffn_b1 + (size_t)l * 4 * DD,
                                                  nullptr, h_b, Mp, 4 * DD, DD, nullptr, DD, 1);
        // FFN2: split-K x3 into qkv_f partials
        gemm_mfma<4><<<3 * MB * 6, 256, 0, stream>>>(h_b, w2, ffn_b2 + (size_t)l * DD,
                                                     qkv_f, nullptr, Mp, DD, 4 * DD, nullptr, 1024, 3);
        ln_kernel<<<M, 256, 0, stream>>>(ctx_f, qkv_f, 3, pstr, ln2_g + (size_t)l * DD,
                                         ln2_b + (size_t)l * DD, ctx_f, ctx_b);
    }
    ln_kernel<<<M, 256, 0, stream>>>(ctx_f, nullptr, 0, 0, norm_g, norm_b, out, nullptr);
}

// Round 5
// 3470.602 us; speedup vs baseline: 1.0841x; 1.0841x over previous
//
#include <hip/hip_runtime.h>
#include <math.h>

// ---- problem constants ----
#define BB 64
#define IMG 224
#define PP 16
#define DD 768
#define NH 12
#define NL 12
#define GG 14
#define TT 196
#define HD 64

typedef __attribute__((ext_vector_type(8))) short short8;
typedef __attribute__((ext_vector_type(4))) float floatx4;

__device__ __forceinline__ unsigned short f2bfu(float f) {
    union { float f; unsigned int u; } v; v.f = f;
    unsigned int r = v.u + 0x7FFFu + ((v.u >> 16) & 1u);   // RNE
    return (unsigned short)(r >> 16);
}

__device__ __forceinline__ void g2lds16(const void* g, void* l) {
    __builtin_amdgcn_global_load_lds(
        (const __attribute__((address_space(1))) unsigned int*)g,
        (__attribute__((address_space(3))) unsigned int*)l, 16, 0, 0);
}

// ================= bf16 MFMA GEMM:  C[M,N] = A[M,K] @ W[N,K]^T + bias =================
// 128x128 tile, BK=32, DOUBLE-BUFFERED 2-phase: stage(t+1) issued before compute(t),
// one __syncthreads (vmcnt+lgkm drain) per K-step. 4 waves, 64x64 each, 4x4 MFMA tiles.
// MODE 0: fp32 out + bias.        MODE 1: bias + exact GELU, bf16 out.
// MODE 2: fp32 out + bias + pos_embed[row % TT].  MODE 3: bias, bf16 out.
// MODE 4: split-K fp32 partials; grid = splits*MB*nb; split s handles K-chunk
//         [s*klen, (s+1)*klen), writes Cf + s*M*N; bias only on split 0.
template <int MODE>
__global__ __launch_bounds__(256) void gemm_mfma(const unsigned short* __restrict__ A,
                                                 const unsigned short* __restrict__ W,
                                                 const float* __restrict__ bias,
                                                 float* __restrict__ Cf,
                                                 unsigned short* __restrict__ Cb,
                                                 int M, int N, int K,
                                                 const float* __restrict__ pose,
                                                 int klen, int splits) {
    __shared__ unsigned short As[2][128 * 32];
    __shared__ unsigned short Bs[2][128 * 32];
    const int nb = N >> 7;
    int bid = blockIdx.x;
    int split = 0;
    if (MODE == 4) {
        const int per = gridDim.x / splits;
        split = bid / per;
        bid -= split * per;
    }
    const int m0 = (bid / nb) << 7;
    const int n0 = (bid % nb) << 7;
    const int tid = threadIdx.x;
    const int lane = tid & 63;
    const int wave = tid >> 6;
    const int wm = (wave >> 1) << 6;
    const int wn = (wave & 1) << 6;
    const int fr = lane & 15;          // frag row (A) / col (B)
    const int fk = (lane >> 4) << 3;   // frag k offset

    const unsigned short* Ag = A + (size_t)(m0 + (tid >> 2)) * K + (tid & 3) * 8;
    const unsigned short* Wg = W + (size_t)(n0 + (tid >> 2)) * K + (tid & 3) * 8;
    const size_t rowskip = (size_t)64 * K;
    const int loff = tid * 8;

    floatx4 acc[4][4];
#pragma unroll
    for (int i = 0; i < 4; ++i)
#pragma unroll
        for (int j = 0; j < 4; ++j) acc[i][j] = (floatx4){0.f, 0.f, 0.f, 0.f};

    const int kstart = (MODE == 4) ? split * klen : 0;
    const int kend = (MODE == 4) ? kstart + klen : K;

    // prologue: stage first tile into buffer 0
    g2lds16(Ag + kstart, &As[0][loff]);
    g2lds16(Ag + kstart + rowskip, &As[0][loff + 64 * 32]);
    g2lds16(Wg + kstart, &Bs[0][loff]);
    g2lds16(Wg + kstart + rowskip, &Bs[0][loff + 64 * 32]);
    __syncthreads();                                   // drains vmcnt(0)

    int cur = 0;
    for (int kt = kstart; kt < kend; kt += 32) {
        // phase A: issue next tile's loads into the other buffer (overlaps compute)
        if (kt + 32 < kend) {
            const int nx = cur ^ 1;
            g2lds16(Ag + kt + 32, &As[nx][loff]);
            g2lds16(Ag + kt + 32 + rowskip, &As[nx][loff + 64 * 32]);
            g2lds16(Wg + kt + 32, &Bs[nx][loff]);
            g2lds16(Wg + kt + 32 + rowskip, &Bs[nx][loff + 64 * 32]);
        }
        // phase B: compute current buffer
        short8 af[4], bf[4];
#pragma unroll
        for (int i = 0; i < 4; ++i) {
            af[i] = *(const short8*)(&As[cur][(wm + i * 16 + fr) * 32 + fk]);
            bf[i] = *(const short8*)(&Bs[cur][(wn + i * 16 + fr) * 32 + fk]);
        }
#pragma unroll
        for (int i = 0; i < 4; ++i)
#pragma unroll
            for (int j = 0; j < 4; ++j)
                acc[i][j] = __builtin_amdgcn_mfma_f32_16x16x32_bf16(af[i], bf[j], acc[i][j], 0, 0, 0);
        __syncthreads();                               // one vmcnt+lgkm drain per K-step
        cur ^= 1;
    }

    float* Cfs = (MODE == 4) ? Cf + (size_t)split * M * N : Cf;
    const int r0 = (lane >> 4) << 2;   // C/D: row=(lane>>4)*4+reg, col=lane&15 (m89-verified)
#pragma unroll
    for (int j = 0; j < 4; ++j) {
        const int col = n0 + wn + j * 16 + fr;
        float bv = bias ? bias[col] : 0.f;
        if (MODE == 4 && split != 0) bv = 0.f;
#pragma unroll
        for (int i = 0; i < 4; ++i) {
            const int row = m0 + wm + i * 16 + r0;
#pragma unroll
            for (int r = 0; r < 4; ++r) {
                float v = acc[i][j][r] + bv;
                if (MODE == 1) {
                    v = 0.5f * v * (1.0f + erff(v * 0.70710678118654752f));
                    Cb[(size_t)(row + r) * N + col] = f2bfu(v);
                } else if (MODE == 2) {
                    const int tok = (row + r) % TT;
                    Cfs[(size_t)(row + r) * N + col] = v + pose[(size_t)tok * DD + col];
                } else if (MODE == 3) {
                    Cb[(size_t)(row + r) * N + col] = f2bfu(v);
                } else {
                    Cfs[(size_t)(row + r) * N + col] = v;
                }
            }
        }
    }
}

// ================= im2col of x into bf16 A[B*T, 768];  k = c*256 + py*16 + px =================
__global__ __launch_bounds__(256) void im2col_bf16(const float* __restrict__ x,
                                                   unsigned short* __restrict__ A) {
    const int u = blockIdx.x * 256 + threadIdx.x;       // total B*T*768/4 = 2408448
    const int m = u / 192;                              // row (b*TT + token)
    const int kq = (u - m * 192) * 4;                   // k offset, multiple of 4
    const int b = m / TT, token = m - b * TT;
    const int gy = token / GG, gx = token - gy * GG;
    const int c = kq >> 8, py = (kq >> 4) & 15, px = kq & 15;
    const float* src = x + ((size_t)b * 3 + c) * (IMG * IMG)
                         + (size_t)(gy * PP + py) * IMG + gx * PP + px;
    float4 v = *(const float4*)src;
    ushort4 o;
    o.x = f2bfu(v.x); o.y = f2bfu(v.y); o.z = f2bfu(v.z); o.w = f2bfu(v.w);
    *(ushort4*)(A + (size_t)m * DD + kq) = o;
}

// ================= patch embedding fp32 fallback =================
__global__ __launch_bounds__(256) void patch_embed_gemm(const float* __restrict__ x,
                                                        const float* __restrict__ W,
                                                        const float* __restrict__ bias,
                                                        const float* __restrict__ pos,
                                                        float* __restrict__ t) {
    __shared__ float Asm[16][68];
    __shared__ float Bsm[16][68];
    const int m0 = (blockIdx.x / 12) * 64;
    const int n0 = (blockIdx.x % 12) * 64;
    const int tid = threadIdx.x;
    const int lr = tid >> 2;
    const int lk = (tid & 3) * 4;
    const int tx = tid & 15, ty = tid >> 4;

    const int m = m0 + lr;
    const int b = m / TT, token = m % TT;
    const int gy = token / GG, gx = token % GG;
    const float* xrow = x + (size_t)b * (3 * IMG * IMG) + (gy * PP) * IMG + gx * PP;

    float acc[4][4] = {};
    for (int kt = 0; kt < 48; ++kt) {
        int c = kt >> 4, py = kt & 15;
        float4 av = *(const float4*)(xrow + ((size_t)c * IMG + py) * IMG + lk);
        float4 bv = *(const float4*)(W + (size_t)(n0 + lr) * DD + kt * 16 + lk);
        __syncthreads();
        Asm[lk + 0][lr] = av.x; Asm[lk + 1][lr] = av.y; Asm[lk + 2][lr] = av.z; Asm[lk + 3][lr] = av.w;
        Bsm[lk + 0][lr] = bv.x; Bsm[lk + 1][lr] = bv.y; Bsm[lk + 2][lr] = bv.z; Bsm[lk + 3][lr] = bv.w;
        __syncthreads();
#pragma unroll
        for (int k = 0; k < 16; ++k) {
            float4 a4 = *(const float4*)&Asm[k][ty * 4];
            float4 b4 = *(const float4*)&Bsm[k][tx * 4];
            float a[4] = {a4.x, a4.y, a4.z, a4.w};
            float b2[4] = {b4.x, b4.y, b4.z, b4.w};
#pragma unroll
            for (int i = 0; i < 4; ++i)
#pragma unroll
                for (int j = 0; j < 4; ++j) acc[i][j] += a[i] * b2[j];
        }
    }
    float4 bi = *(const float4*)(bias + n0 + tx * 4);
#pragma unroll
    for (int i = 0; i < 4; ++i) {
        int mi = m0 + ty * 4 + i;
        int tok = mi % TT;
        float4 p4 = *(const float4*)(pos + (size_t)tok * DD + n0 + tx * 4);
        float4 o;
        o.x = acc[i][0] + bi.x + p4.x;
        o.y = acc[i][1] + bi.y + p4.y;
        o.z = acc[i][2] + bi.z + p4.z;
        o.w = acc[i][3] + bi.w + p4.w;
        *(float4*)(t + (size_t)mi * DD + n0 + tx * 4) = o;
    }
}

// ================= mask scan: order list + lengths + pad flags (wave-parallel) =================
__global__ __launch_bounds__(64) void scan_mask(const unsigned char* __restrict__ mask8,
                                                int* __restrict__ order,
                                                int* __restrict__ lengths,
                                                float* __restrict__ pad_out, int Sc) {
    const int b = blockIdx.x;
    const int lane = threadIdx.x;
    const unsigned int* w = (const unsigned int*)mask8;
    unsigned int v0 = w[lane];
    unsigned long long bf = __ballot(v0 == 0x3F800000u);
    unsigned long long bg = __ballot(v0 != 0x3F800000u && v0 > 1u);
    const int mode = bf ? 2 : (bg ? 1 : 0);   // 0=int32, 1=uint8, 2=float32
    int cnt = 0;
    for (int i0 = 0; i0 < TT; i0 += 64) {
        const int i = i0 + lane;
        int mv = 0;
        if (i < TT) {
            if (mode == 0) mv = mask8[4 * (b * TT + i)];
            else if (mode == 1) mv = mask8[b * TT + i];
            else mv = (w[b * TT + i] != 0u);
        }
        unsigned long long bal = __ballot(mv != 0);
        int pre = __popcll(bal & ((1ull << lane) - 1ull));
        if (mv) order[b * Sc + cnt + pre] = i;
        cnt += __popcll(bal);
    }
    if (lane == 0) lengths[b] = cnt;
    for (int s = lane; s < Sc; s += 64) pad_out[b * Sc + s] = (s < cnt) ? 0.f : 1.f;
}

// ================= gathered copy: fp32 ctx + bf16 ctx, grid-stride float4 =================
__global__ __launch_bounds__(256) void gather_copy(const float* __restrict__ t,
                                                   const int* __restrict__ order,
                                                   const int* __restrict__ lengths,
                                                   float* __restrict__ ctx,
                                                   unsigned short* __restrict__ ctxb, int Sc) {
    const int total = BB * Sc * (DD / 4);
    for (int u = blockIdx.x * 256 + threadIdx.x; u < total; u += gridDim.x * 256) {
        const int row = u / 192, q = u - row * 192;
        const int b = row / Sc, s = row - b * Sc;
        float4 v = {0.f, 0.f, 0.f, 0.f};
        if (s < lengths[b])
            v = *(const float4*)(t + ((size_t)b * TT + order[b * Sc + s]) * DD + q * 4);
        *(float4*)(ctx + (size_t)row * DD + q * 4) = v;
        ushort4 o;
        o.x = f2bfu(v.x); o.y = f2bfu(v.y); o.z = f2bfu(v.z); o.w = f2bfu(v.w);
        *(ushort4*)(ctxb + (size_t)row * DD + q * 4) = o;
    }
}

// ================= MFMA flash attention (Sc <= 128): block=(b,h), 4 waves =================
template <int P>
__global__ __launch_bounds__(256) void attn_mfma(const unsigned short* __restrict__ qkv,
                                                 const int* __restrict__ lengths,
                                                 unsigned short* __restrict__ outp, int Sc) {
    constexpr int PS = 64 * P;
    constexpr int KROW = 128;        // Kb row bytes (64 bf16)
    constexpr int VROW = PS * 2;     // Vt/Pw row bytes
    extern __shared__ unsigned char smraw[];
    unsigned char* Kb = smraw;                   // [PS][KROW]
    unsigned char* Vt = Kb + PS * KROW;          // [64][VROW]
    unsigned char* Pw = Vt + 64 * VROW;          // [4][16P][VROW]
    const int b = blockIdx.x / NH, h = blockIdx.x % NH;
    const int len = lengths[b];
    const int tid = threadIdx.x;
    const int lane = tid & 63, wave = tid >> 6;
    const int fr = lane & 15, g = lane >> 4;
    const size_t qbase = (size_t)b * Sc * (3 * DD) + h * HD;

    for (int c = tid; c < PS * 8; c += 256) {
        const int s = c >> 3, kg = c & 7;
        short8 kv = {0, 0, 0, 0, 0, 0, 0, 0};
        short8 vv = {0, 0, 0, 0, 0, 0, 0, 0};
        if (s < len) {
            kv = *(const short8*)(qkv + qbase + (size_t)s * (3 * DD) + DD + kg * 8);
            vv = *(const short8*)(qkv + qbase + (size_t)s * (3 * DD) + 2 * DD + kg * 8);
        }
        *(short8*)(Kb + s * KROW + ((kg * 16) ^ ((s & 7) << 4))) = kv;
#pragma unroll
        for (int e = 0; e < 8; ++e) {
            const int d = kg * 8 + e;
            *(unsigned short*)(Vt + d * VROW + ((s * 2) ^ ((d & 7) << 4))) =
                (unsigned short)vv[e];
        }
    }
    __syncthreads();

    const int wq0 = wave * 16 * P;
    short8 qf[P][2];
#pragma unroll
    for (int i = 0; i < P; ++i) {
        int qr = wq0 + i * 16 + fr; if (qr >= Sc) qr = Sc - 1;
#pragma unroll
        for (int ks = 0; ks < 2; ++ks)
            qf[i][ks] = *(const short8*)(qkv + qbase + (size_t)qr * (3 * DD) + ks * 32 + g * 8);
    }

    floatx4 sacc[P][4 * P];
#pragma unroll
    for (int i = 0; i < P; ++i)
#pragma unroll
        for (int j = 0; j < 4 * P; ++j) sacc[i][j] = (floatx4){0.f, 0.f, 0.f, 0.f};
#pragma unroll
    for (int j = 0; j < 4 * P; ++j) {
        const int key = j * 16 + fr;
#pragma unroll
        for (int ks = 0; ks < 2; ++ks) {
            short8 kf = *(const short8*)(Kb + key * KROW + ((ks * 64 + g * 16) ^ ((key & 7) << 4)));
#pragma unroll
            for (int i = 0; i < P; ++i)
                sacc[i][j] = __builtin_amdgcn_mfma_f32_16x16x32_bf16(qf[i][ks], kf, sacc[i][j], 0, 0, 0);
        }
    }

    unsigned char* mypw = Pw + (size_t)wave * (16 * P) * VROW;
#pragma unroll
    for (int i = 0; i < P; ++i) {
#pragma unroll
        for (int r = 0; r < 4; ++r) {
            float vals[4 * P];
            float vmax = -1e30f;
#pragma unroll
            for (int j = 0; j < 4 * P; ++j) {
                float s = sacc[i][j][r] * 0.125f;
                if (j * 16 + fr >= len) s = -1e30f;
                vals[j] = s;
                vmax = fmaxf(vmax, s);
            }
#pragma unroll
            for (int off = 1; off < 16; off <<= 1) vmax = fmaxf(vmax, __shfl_xor(vmax, off, 64));
            float lsum = 0.f;
#pragma unroll
            for (int j = 0; j < 4 * P; ++j) { vals[j] = __expf(vals[j] - vmax); lsum += vals[j]; }
#pragma unroll
            for (int off = 1; off < 16; off <<= 1) lsum += __shfl_xor(lsum, off, 64);
            const float rl = 1.0f / lsum;
            const int lr = i * 16 + g * 4 + r;
            unsigned char* rowp = mypw + lr * VROW;
            const int sw = (lr & 7) << 4;
#pragma unroll
            for (int j = 0; j < 4 * P; ++j)
                *(unsigned short*)(rowp + (((j * 16 + fr) * 2) ^ sw)) = f2bfu(vals[j] * rl);
        }
    }

    floatx4 oacc[P][4];
#pragma unroll
    for (int i = 0; i < P; ++i)
#pragma unroll
        for (int dt = 0; dt < 4; ++dt) oacc[i][dt] = (floatx4){0.f, 0.f, 0.f, 0.f};
#pragma unroll
    for (int kk = 0; kk < 2 * P; ++kk) {
        short8 pa[P];
#pragma unroll
        for (int i = 0; i < P; ++i) {
            const int lr = i * 16 + fr;
            pa[i] = *(const short8*)(mypw + lr * VROW + ((kk * 64 + g * 16) ^ ((lr & 7) << 4)));
        }
#pragma unroll
        for (int dt = 0; dt < 4; ++dt) {
            const int d = dt * 16 + fr;
            short8 vb = *(const short8*)(Vt + d * VROW + ((kk * 64 + g * 16) ^ ((d & 7) << 4)));
#pragma unroll
            for (int i = 0; i < P; ++i)
                oacc[i][dt] = __builtin_amdgcn_mfma_f32_16x16x32_bf16(pa[i], vb, oacc[i][dt], 0, 0, 0);
        }
    }

#pragma unroll
    for (int i = 0; i < P; ++i) {
#pragma unroll
        for (int r = 0; r < 4; ++r) {
            const int qr = wq0 + i * 16 + g * 4 + r;
            if (qr < Sc) {
#pragma unroll
                for (int dt = 0; dt < 4; ++dt)
                    outp[((size_t)b * Sc + qr) * DD + h * HD + dt * 16 + fr] = f2bfu(oacc[i][dt][r]);
            }
        }
    }
}

// ================= attention VALU fallback (Sc > 128) =================
template <int P>   // P = ceil(Sc/64), Ks has P*64 rows
__global__ __launch_bounds__(512) void attn_v3(const float* __restrict__ qkv,
                                               const int* __restrict__ lengths,
                                               unsigned short* __restrict__ outp, int Sc) {
    extern __shared__ float smem[];
    float* pst = smem;                       // [8][P*64]
    float* qst = pst + 8 * P * 64;           // [8][66]
    float* Ks  = qst + 8 * 66;               // [P*64][66]
    float* Vs  = Ks + P * 64 * 66;           // [Sc][66]
    const int b = blockIdx.x / NH, h = blockIdx.x % NH;
    const int len = lengths[b];
    const int tid = threadIdx.x;
    const float* base = qkv + (size_t)b * Sc * (3 * DD) + h * HD;

    for (int idx = tid; idx < Sc * HD; idx += 512) {
        int s = idx >> 6, d = idx & 63;
        Ks[s * 66 + d] = base[(size_t)s * (3 * DD) + DD + d];
        Vs[s * 66 + d] = base[(size_t)s * (3 * DD) + 2 * DD + d];
    }
    __syncthreads();

    const int wave = tid >> 6, lane = tid & 63;
    float* qw = qst + wave * 66;
    float* pw = pst + wave * P * 64;

    for (int q = wave; q < Sc; q += 8) {
        float qv = base[(size_t)q * (3 * DD) + lane];
        qw[lane] = qv;
        float s0 = 0.f, s1 = 0.f, s2 = 0.f, s3 = 0.f;
#pragma unroll
        for (int d0 = 0; d0 < 64; d0 += 2) {
            float2 q2 = *(const float2*)(qw + d0);
            float2 k0 = *(const float2*)(Ks + lane * 66 + d0);
            s0 += q2.x * k0.x + q2.y * k0.y;
            if (P > 1) {
                float2 k1 = *(const float2*)(Ks + (lane + 64) * 66 + d0);
                s1 += q2.x * k1.x + q2.y * k1.y;
            }
            if (P > 2) {
                float2 k2 = *(const float2*)(Ks + (lane + 128) * 66 + d0);
                s2 += q2.x * k2.x + q2.y * k2.y;
            }
            if (P > 3) {
                float2 k3 = *(const float2*)(Ks + (lane + 192) * 66 + d0);
                s3 += q2.x * k3.x + q2.y * k3.y;
            }
        }
        s0 = (lane < len) ? s0 * 0.125f : -1e30f;
        if (P > 1) s1 = (64 + lane < len) ? s1 * 0.125f : -1e30f;
        if (P > 2) s2 = (128 + lane < len) ? s2 * 0.125f : -1e30f;
        if (P > 3) s3 = (192 + lane < len) ? s3 * 0.125f : -1e30f;
        float m = s0;
        if (P > 1) m = fmaxf(m, s1);
        if (P > 2) m = fmaxf(m, s2);
        if (P > 3) m = fmaxf(m, s3);
#pragma unroll
        for (int off = 32; off; off >>= 1) m = fmaxf(m, __shfl_xor(m, off, 64));
        s0 = __expf(s0 - m);
        if (P > 1) s1 = __expf(s1 - m);
        if (P > 2) s2 = __expf(s2 - m);
        if (P > 3) s3 = __expf(s3 - m);
        float l = s0;
        if (P > 1) l += s1;
        if (P > 2) l += s2;
        if (P > 3) l += s3;
#pragma unroll
        for (int off = 32; off; off >>= 1) l += __shfl_xor(l, off, 64);
        pw[lane] = s0;
        if (P > 1) pw[64 + lane] = s1;
        if (P > 2) pw[128 + lane] = s2;
        if (P > 3) pw[192 + lane] = s3;
        float a0 = 0.f, a1 = 0.f, a2 = 0.f, a3 = 0.f;
        const int j4 = len & ~3;
        for (int j = 0; j < j4; j += 4) {
            float4 p4 = *(const float4*)(pw + j);
            a0 += p4.x * Vs[(j + 0) * 66 + lane];
            a1 += p4.y * Vs[(j + 1) * 66 + lane];
            a2 += p4.z * Vs[(j + 2) * 66 + lane];
            a3 += p4.w * Vs[(j + 3) * 66 + lane];
        }
        for (int j = j4; j < len; ++j) a0 += pw[j] * Vs[j * 66 + lane];
        float acc = (a0 + a1) + (a2 + a3);
        outp[((size_t)b * Sc + q) * DD + h * HD + lane] = f2bfu(acc / l);
    }
}

// ================= layernorm (+residual = x + sum of nparts partials) =================
__global__ __launch_bounds__(256) void ln_kernel(const float* __restrict__ x,
                                                 const float* __restrict__ parts,
                                                 int nparts, size_t pstride,
                                                 const float* __restrict__ g,
                                                 const float* __restrict__ beta,
                                                 float* __restrict__ outf,
                                                 unsigned short* __restrict__ outb) {
    __shared__ float red[4];
    const size_t row = blockIdx.x;
    const int tid = threadIdx.x;
    float v[3];
#pragma unroll
    for (int i = 0; i < 3; ++i) {
        int d = tid + i * 256;
        float t0 = x[row * DD + d];
        for (int s = 0; s < nparts; ++s) t0 += parts[s * pstride + row * DD + d];
        v[i] = t0;
    }
    float s = v[0] + v[1] + v[2];
#pragma unroll
    for (int off = 32; off; off >>= 1) s += __shfl_xor(s, off, 64);
    if ((tid & 63) == 0) red[tid >> 6] = s;
    __syncthreads();
    float mean = (red[0] + red[1] + red[2] + red[3]) * (1.0f / 768.0f);
    __syncthreads();
    float vs = 0.f;
#pragma unroll
    for (int i = 0; i < 3; ++i) { float d0 = v[i] - mean; vs += d0 * d0; }
#pragma unroll
    for (int off = 32; off; off >>= 1) vs += __shfl_xor(vs, off, 64);
    if ((tid & 63) == 0) red[tid >> 6] = vs;
    __syncthreads();
    float var = (red[0] + red[1] + red[2] + red[3]) * (1.0f / 768.0f);
    float inv = rsqrtf(var + 1e-5f);
#pragma unroll
    for (int i = 0; i < 3; ++i) {
        int d = tid + i * 256;
        float o = (v[i] - mean) * inv * g[d] + beta[d];
        outf[row * DD + d] = o;
        if (outb) outb[row * DD + d] = f2bfu(o);
    }
}

// ================= fp32 -> bf16 conversion of up to 4 weight mats =================
__global__ __launch_bounds__(256) void convert4_bf16(const float* __restrict__ a, int na,
                                                     const float* __restrict__ b, int nb,
                                                     const float* __restrict__ c, int nc,
                                                     const float* __restrict__ d, int nd,
                                                     unsigned short* __restrict__ dst) {
    const int total4 = (na + nb + nc + nd) >> 2;
    for (int u = blockIdx.x * 256 + threadIdx.x; u < total4; u += gridDim.x * 256) {
        int e = u << 2;
        const float* src; int off;
        if (e < na) { src = a; off = e; }
        else if (e < na + nb) { src = b; off = e - na; }
        else if (e < na + nb + nc) { src = c; off = e - na - nb; }
        else { src = d; off = e - na - nb - nc; }
        float4 v = *(const float4*)(src + off);
        ushort4 o;
        o.x = f2bfu(v.x); o.y = f2bfu(v.y); o.z = f2bfu(v.z); o.w = f2bfu(v.w);
        *(ushort4*)(dst + e) = o;
    }
}

extern "C" void kernel_launch(void* const* d_in, const int* in_sizes, int n_in,
                              void* d_out, int out_size, void* d_ws, size_t ws_size,
                              hipStream_t stream) {
    (void)in_sizes; (void)n_in; (void)ws_size;
    const float* x          = (const float*)d_in[0];
    const unsigned char* mk = (const unsigned char*)d_in[1];
    const float* patch_w    = (const float*)d_in[2];
    const float* patch_b    = (const float*)d_in[3];
    const float* pos        = (const float*)d_in[4];
    const float* in_proj_w  = (const float*)d_in[5];
    const float* in_proj_b  = (const float*)d_in[6];
    const float* out_w      = (const float*)d_in[7];
    const float* out_b      = (const float*)d_in[8];
    const float* ln1_g      = (const float*)d_in[9];
    const float* ln1_b      = (const float*)d_in[10];
    const float* ffn_w1     = (const float*)d_in[11];
    const float* ffn_b1     = (const float*)d_in[12];
    const float* ffn_w2     = (const float*)d_in[13];
    const float* ffn_b2     = (const float*)d_in[14];
    const float* ln2_g      = (const float*)d_in[15];
    const float* ln2_b      = (const float*)d_in[16];
    const float* norm_g     = (const float*)d_in[17];
    const float* norm_b     = (const float*)d_in[18];
    float* out = (float*)d_out;

    const int Sc = out_size / (BB * (DD + 1));
    const int M = BB * Sc;
    const int Mp = ((M + 127) / 128) * 128;
    const int MB = Mp / 128;

    // ---- workspace layout ----
    float* t_f   = (float*)d_ws;                          // B*T*D
    float* qkv_f = t_f + (size_t)BB * TT * DD;            // Mp*2304 (also split-K partials)
    float* ctx_f = qkv_f + (size_t)Mp * 2304;             // Mp*768
    float* y_f   = ctx_f + (size_t)Mp * DD;               // Mp*768 (unused on split path)
    unsigned short* ctx_b  = (unsigned short*)(y_f + (size_t)Mp * DD);  // Mp*768
    unsigned short* attn_b = ctx_b + (size_t)Mp * DD;                    // Mp*768
    unsigned short* h_b    = attn_b + (size_t)Mp * DD;                   // Mp*3072
    unsigned short* wq     = h_b + (size_t)Mp * 4 * DD;                  // 2304*768
    unsigned short* wo     = wq + (size_t)3 * DD * DD;                   // 768*768
    unsigned short* w1     = wo + (size_t)DD * DD;                       // 3072*768
    unsigned short* w2     = w1 + (size_t)4 * DD * DD;                   // 768*3072
    int* lengths = (int*)(w2 + (size_t)4 * DD * DD);
    unsigned short* qkv_b = (unsigned short*)qkv_f;       // bf16 alias (MFMA attn path)
    int* order = (int*)qkv_f;  // scratch alias: dead between patch gemm and layer-0 QKV
    const size_t pstr = (size_t)Mp * DD;                  // split-K partial stride

    // ---- patch embedding (bf16 MFMA fast path) ----
    const bool fast_patch =
        ((size_t)Mp * 2304 * sizeof(float) >= (size_t)BB * TT * DD * sizeof(unsigned short)) &&
        ((size_t)Mp * DD * sizeof(unsigned short) >= (size_t)DD * DD * sizeof(unsigned short));
    if (fast_patch) {
        unsigned short* Apatch = ((unsigned short*)qkv_f) + (size_t)BB * 256;  // keep order area clear
        unsigned short* wpatch = ctx_b;
        im2col_bf16<<<(BB * TT * DD / 4) / 256, 256, 0, stream>>>(x, Apatch);
        convert4_bf16<<<1024, 256, 0, stream>>>(patch_w, DD * DD, nullptr, 0,
                                                nullptr, 0, nullptr, 0, wpatch);
        gemm_mfma<2><<<(BB * TT / 128) * (DD / 128), 256, 0, stream>>>(
            Apatch, wpatch, patch_b, t_f, nullptr, BB * TT, DD, DD, pos, DD, 1);
        order = (int*)(Apatch + (size_t)BB * TT * DD);   // after A, still inside qkv_f
    } else {
        patch_embed_gemm<<<TT * 12, 256, 0, stream>>>(x, patch_w, patch_b, pos, t_f);
    }
    scan_mask<<<BB, 64, 0, stream>>>(mk, order, lengths, out + (size_t)M * DD, Sc);
    {
        int total4 = BB * Sc * (DD / 4);
        int gblocks = (total4 + 255) / 256; if (gblocks > 2048) gblocks = 2048;
        gather_copy<<<gblocks, 256, 0, stream>>>(t_f, order, lengths, ctx_f, ctx_b, Sc);
    }

    int P = (Sc + 63) / 64; if (P > 4) P = 4;
    const bool mfma_attn = (P <= 2);
    size_t smem_attn;
    if (mfma_attn) {
        smem_attn = (size_t)(64 * P) * 128 * (2 + P);
        const void* fp = (P == 1) ? (const void*)attn_mfma<1> : (const void*)attn_mfma<2>;
        (void)hipFuncSetAttribute(fp, hipFuncAttributeMaxDynamicSharedMemorySize, (int)smem_attn);
    } else {
        smem_attn = (size_t)(8 * P * 64 + 8 * 66 + (size_t)(P * 64 + Sc) * 66) * sizeof(float);
        const void* fp = (P == 3) ? (const void*)attn_v3<3> : (const void*)attn_v3<4>;
        (void)hipFuncSetAttribute(fp, hipFuncAttributeMaxDynamicSharedMemorySize, (int)smem_attn);
    }

    for (int l = 0; l < NL; ++l) {
        convert4_bf16<<<1024, 256, 0, stream>>>(
            in_proj_w + (size_t)l * 3 * DD * DD, 3 * DD * DD,
            out_w + (size_t)l * DD * DD, DD * DD,
            ffn_w1 + (size_t)l * 4 * DD * DD, 4 * DD * DD,
            ffn_w2 + (size_t)l * 4 * DD * DD, 4 * DD * DD, wq);
        if (mfma_attn) {
            gemm_mfma<3><<<MB * 18, 256, 0, stream>>>(ctx_b, wq, in_proj_b + (size_t)l * 3 * DD,
                                                      nullptr, qkv_b, Mp, 3 * DD, DD, nullptr, DD, 1);
            if (P == 1)
                attn_mfma<1><<<BB * NH, 256, smem_attn, stream>>>(qkv_b, lengths, attn_b, Sc);
            else
                attn_mfma<2><<<BB * NH, 256, smem_attn, stream>>>(qkv_b, lengths, attn_b, Sc);
        } else {
            gemm_mfma<0><<<MB * 18, 256, 0, stream>>>(ctx_b, wq, in_proj_b + (size_t)l * 3 * DD,
                                                      qkv_f, nullptr, Mp, 3 * DD, DD, nullptr, DD, 1);
            if (P == 3)
                attn_v3<3><<<BB * NH, 512, smem_attn, stream>>>(qkv_f, lengths, attn_b, Sc);
            else
                attn_v3<4><<<BB * NH, 512, smem_attn, stream>>>(qkv_f, lengths, attn_b, Sc);
        }
        // WO: split-K x2 into qkv_f partials (qkv consumed by attn already)
        gemm_mfma<4><<<2 * MB * 6, 256, 0, stream>>>(attn_b, wo, out_b + (size_t)l * DD,
                                                     qkv_f, nullptr, Mp, DD, DD, nullptr, 384, 2);
        ln_kernel<<<M, 256, 0, stream>>>(ctx_f, qkv_f, 2, pstr, ln1_g + (size_t)l * DD,
                                         ln1_b + (size_t)l * DD, ctx_f, ctx_b);
        gemm_mfma<1><<<MB * 24, 256, 0, stream>>>(ctx_b, w1, ffn_b1 + (size_t)l * 4 * DD,
                                                  nullptr, h_b, Mp, 4 * DD, DD, nullptr, DD, 1);
        // FFN2: split-K x2 into qkv_f partials
        gemm_mfma<4><<<2 * MB * 6, 256, 0, stream>>>(h_b, w2, ffn_b2 + (size_t)l * DD,
                                                     qkv_f, nullptr, Mp, DD, 4 * DD, nullptr, 1536, 2);
        ln_kernel<<<M, 256, 0, stream>>>(ctx_f, qkv_f, 2, pstr, ln2_g + (size_t)l * DD,
                                         ln2_b + (size_t)l * DD, ctx_f, ctx_b);
    }
    ln_kernel<<<M, 256, 0, stream>>>(ctx_f, nullptr, 0, 0, norm_g, norm_b, out, nullptr);
}